// Round 3
// baseline (1522.817 us; speedup 1.0000x reference)
//
#include <hip/hip_runtime.h>
#include <stdint.h>

typedef unsigned short u16;
typedef float f32x4 __attribute__((ext_vector_type(4)));
typedef __bf16 bf16x8 __attribute__((ext_vector_type(8)));
typedef u16 u16x4 __attribute__((ext_vector_type(4)));

#define DEVI static __device__ __forceinline__

constexpr int NN  = 131072;   // batch
constexpr int DI  = 1024;     // d_in
constexpr int DOUT= 1024;     // d_out
constexpr int BB  = 2048;     // segments
constexpr float EPS = 1e-5f;

DEVI u16 f2bf(float f) {
  unsigned u = __builtin_bit_cast(unsigned, f);
  u += 0x7fffu + ((u >> 16) & 1u);            // RNE
  return (u16)(u >> 16);
}
DEVI float bf2f(u16 h) { return __builtin_bit_cast(float, ((unsigned)h) << 16); }

DEVI int lowb(const int* __restrict__ a, int n, int v) {
  int lo = 0, hi = n;
  while (lo < hi) { int mid = (lo + hi) >> 1; if (a[mid] < v) lo = mid + 1; else hi = mid; }
  return lo;
}

// ---------------------------------------------------------------------------
// K1: per-segment sum of x (sorted seg_ids -> one block per segment) fused
// with f32 -> bf16 conversion of x.  No atomics, covers every row exactly once.
// ---------------------------------------------------------------------------
__global__ __launch_bounds__(256)
void k_segsum(const float* __restrict__ x, const int* __restrict__ seg,
              u16* __restrict__ xbf, u16* __restrict__ xmbf)
{
  const int b = blockIdx.x, t = threadIdx.x;
  const int lo = lowb(seg, NN, b);
  const int hi = lowb(seg, NN, b + 1);
  float a0 = 0.f, a1 = 0.f, a2 = 0.f, a3 = 0.f;
  for (int r = lo; r < hi; ++r) {
    const float4 v = ((const float4*)(x + (size_t)r * DI))[t];
    a0 += v.x; a1 += v.y; a2 += v.z; a3 += v.w;
    u16x4 u; u[0] = f2bf(v.x); u[1] = f2bf(v.y); u[2] = f2bf(v.z); u[3] = f2bf(v.w);
    *(u16x4*)(xbf + (size_t)r * DI + t * 4) = u;
  }
  u16x4 m; m[0] = f2bf(a0); m[1] = f2bf(a1); m[2] = f2bf(a2); m[3] = f2bf(a3);
  *(u16x4*)(xmbf + (size_t)b * DI + t * 4) = m;
}

// ---------------------------------------------------------------------------
// K1b: convert both weight matrices to bf16 (8 MB read, trivial)
// ---------------------------------------------------------------------------
__global__ __launch_bounds__(256)
void k_convw(const float* __restrict__ wf, const float* __restrict__ wsh,
             u16* __restrict__ wfb, u16* __restrict__ wshb)
{
  const int PER = DOUT * DI / 4;             // float4 slots per matrix
  int i = blockIdx.x * 256 + threadIdx.x;    // grid covers 2*PER
  const float* src = (i < PER) ? wf : wsh;
  u16* dst = (i < PER) ? wfb : wshb;
  int j = (i < PER) ? i : i - PER;
  float4 v = ((const float4*)src)[j];
  u16x4 u; u[0] = f2bf(v.x); u[1] = f2bf(v.y); u[2] = f2bf(v.z); u[3] = f2bf(v.w);
  *(u16x4*)(dst + (size_t)j * 4) = u;
}

// ---------------------------------------------------------------------------
// K2/K3: bf16 MFMA GEMM, Z = A @ W^T (no bias -- it cancels in BN), storing Z
// plus deterministic per-block column sum/sumsq partials.
// 128x128 tile, BK=32, 4 waves (2x2), 16x16x32 MFMA, global_load_lds width 16.
// LDS XOR swizzle (rule #21: linear LDS dest + inverse-swizzled global source
// + swizzled ds_read).
// ---------------------------------------------------------------------------
template<int MT, bool ZBF>
__global__ __launch_bounds__(256)
void gemm_kernel(const u16* __restrict__ A, const u16* __restrict__ W,
                 void* __restrict__ Z, float* __restrict__ psum, float* __restrict__ psq)
{
  __shared__ u16 As[2][128][32];
  __shared__ u16 Bs[2][128][32];
  __shared__ float redS[4][4][16];
  __shared__ float redQ[4][4][16];

  const int tid = threadIdx.x;
  const int lane = tid & 63;
  const int wid = tid >> 6;
  const int l16 = lane & 15, lhi = lane >> 4;
  const int wr = wid >> 1, wc = wid & 1;

  // XCD-bijective swizzle: consecutive same-A-panel blocks land on one XCD.
  const int bid = blockIdx.x;
  const int xcd = bid & 7, local = bid >> 3;
  const int mt = xcd * (MT / 8) + (local >> 3);
  const int nt = local & 7;
  const int m0 = mt * 128, n0 = nt * 128;

  // staging: lane l writes LDS bytes [16l,16l+16) of a 16-row slice.
  // LDS row_local = l>>2, LDS slot = l&3 ; global slot = (l&3) ^ (row_local&3)
  const int srow = lane >> 2;
  const int sslot = (lane & 3) ^ (srow & 3);
  const u16* gA0 = A + (size_t)(m0 + srow) * DI + sslot * 8;
  const u16* gB0 = W + (size_t)(n0 + srow) * DI + sslot * 8;

  f32x4 acc[4][4] = {};

  auto stage = [&](int bufi, int kt) {
    const int k0 = kt * 32;
#pragma unroll
    for (int s2 = 0; s2 < 2; ++s2) {
      const int s = wid + s2 * 4;                 // wave-uniform slice id
      __builtin_amdgcn_global_load_lds(
          (const __attribute__((address_space(1))) void*)(gA0 + (size_t)s * 16 * DI + k0),
          (__attribute__((address_space(3))) void*)(&As[bufi][s * 16][0]), 16, 0, 0);
      __builtin_amdgcn_global_load_lds(
          (const __attribute__((address_space(1))) void*)(gB0 + (size_t)s * 16 * DI + k0),
          (__attribute__((address_space(3))) void*)(&Bs[bufi][s * 16][0]), 16, 0, 0);
    }
  };

  stage(0, 0);
  __syncthreads();
  int buf = 0;
  const int NK = DI / 32;
  for (int kt = 0; kt < NK; ++kt) {
    if (kt + 1 < NK) stage(buf ^ 1, kt + 1);
    bf16x8 a[4], b[4];
#pragma unroll
    for (int mi = 0; mi < 4; ++mi) {
      const int row = wr * 64 + mi * 16 + l16;
      a[mi] = *(const bf16x8*)&As[buf][row][8 * (lhi ^ (row & 3))];
    }
#pragma unroll
    for (int ni = 0; ni < 4; ++ni) {
      const int row = wc * 64 + ni * 16 + l16;
      b[ni] = *(const bf16x8*)&Bs[buf][row][8 * (lhi ^ (row & 3))];
    }
#pragma unroll
    for (int mi = 0; mi < 4; ++mi)
#pragma unroll
      for (int ni = 0; ni < 4; ++ni)
        acc[mi][ni] = __builtin_amdgcn_mfma_f32_16x16x32_bf16(a[mi], b[ni], acc[mi][ni], 0, 0, 0);
    __syncthreads();
    buf ^= 1;
  }

  // ---- per-column partial stats (sum, sumsq over this block's 128 rows) ----
  // C/D layout (m89-verified): col = lane&15, row = (lane>>4)*4 + reg
#pragma unroll
  for (int ni = 0; ni < 4; ++ni) {
    float s = 0.f, q = 0.f;
#pragma unroll
    for (int mi = 0; mi < 4; ++mi)
#pragma unroll
      for (int r = 0; r < 4; ++r) { const float v = acc[mi][ni][r]; s += v; q += v * v; }
    s += __shfl_xor(s, 16); s += __shfl_xor(s, 32);
    q += __shfl_xor(q, 16); q += __shfl_xor(q, 32);
    if (lhi == 0) { redS[wid][ni][l16] = s; redQ[wid][ni][l16] = q; }
  }
  __syncthreads();
  if (tid < 128) {
    const int wc2 = tid >> 6, ni = (tid >> 4) & 3, c = tid & 15;
    const float s = redS[wc2][ni][c] + redS[wc2 + 2][ni][c];
    const float q = redQ[wc2][ni][c] + redQ[wc2 + 2][ni][c];
    const int col = n0 + wc2 * 64 + ni * 16 + c;
    psum[(size_t)mt * DOUT + col] = s;
    psq [(size_t)mt * DOUT + col] = q;
  }

  // ---- store Z ----
#pragma unroll
  for (int mi = 0; mi < 4; ++mi)
#pragma unroll
    for (int ni = 0; ni < 4; ++ni)
#pragma unroll
      for (int r = 0; r < 4; ++r) {
        const int row = m0 + wr * 64 + mi * 16 + lhi * 4 + r;
        const int col = n0 + wc * 64 + ni * 16 + l16;
        const float v = acc[mi][ni][r];
        if (ZBF) ((u16*)Z)[(size_t)row * DOUT + col] = f2bf(v);
        else     ((float*)Z)[(size_t)row * DOUT + col] = v;
      }
}

// ---------------------------------------------------------------------------
// K2b: reduce partials -> scale/shift per column.
// scale = g * rsqrt(var+eps), shift = be - mean*scale   (bias-free z)
// ---------------------------------------------------------------------------
__global__ __launch_bounds__(256)
void k_finalize(const float* __restrict__ psum, const float* __restrict__ psq,
                int nparts, float invN,
                const float* __restrict__ g, const float* __restrict__ be,
                float* __restrict__ scale, float* __restrict__ shift)
{
  __shared__ float ls[4][64], lq[4][64];
  const int c0 = blockIdx.x * 64;
  const int c = threadIdx.x & 63, grp = threadIdx.x >> 6;
  float s = 0.f, q = 0.f;
  for (int r = grp; r < nparts; r += 4) {
    s += psum[(size_t)r * DOUT + c0 + c];
    q += psq [(size_t)r * DOUT + c0 + c];
  }
  ls[grp][c] = s; lq[grp][c] = q;
  __syncthreads();
  if (grp == 0) {
    s = ls[0][c] + ls[1][c] + ls[2][c] + ls[3][c];
    q = lq[0][c] + lq[1][c] + lq[2][c] + lq[3][c];
    const float m = s * invN;
    const float v = fmaxf(q * invN - m * m, 0.f);
    const float rr = rsqrtf(v + EPS);
    const float sc = g[c0 + c] * rr;
    scale[c0 + c] = sc;
    shift[c0 + c] = be[c0 + c] - m * sc;
  }
}

// ---------------------------------------------------------------------------
// K4: out[n][j] = z[n][j]*scale_fc[j] + shift_fc[j]
//               + z_s[seg[n]][j]*scale_sh[j] + shift_sh[j]
// z_s is 8 MB -> L2/L3-resident gather. Works in-place when z == out (f32).
// ---------------------------------------------------------------------------
template<bool ZBF>
__global__ __launch_bounds__(256)
void k_epilogue(const void* __restrict__ z, const float* __restrict__ zs,
                const int* __restrict__ seg,
                const float* __restrict__ scf, const float* __restrict__ shf,
                const float* __restrict__ scs, const float* __restrict__ shs,
                float* __restrict__ out)
{
  const int t = threadIdx.x;
  const float4 af = ((const float4*)scf)[t];
  const float4 bf = ((const float4*)shf)[t];
  const float4 as = ((const float4*)scs)[t];
  const float4 bs = ((const float4*)shs)[t];
  const int r0 = blockIdx.x * 16;
  for (int i = 0; i < 16; ++i) {
    const int r = r0 + i;
    const int sg = seg[r];
    const float4 vs = ((const float4*)(zs + (size_t)sg * DOUT))[t];
    float4 zi;
    if (ZBF) {
      const u16x4 u = *(const u16x4*)((const u16*)z + (size_t)r * DOUT + t * 4);
      zi.x = bf2f(u[0]); zi.y = bf2f(u[1]); zi.z = bf2f(u[2]); zi.w = bf2f(u[3]);
    } else {
      zi = ((const float4*)((const float*)z + (size_t)r * DOUT))[t];
    }
    float4 o;
    o.x = zi.x * af.x + bf.x + vs.x * as.x + bs.x;
    o.y = zi.y * af.y + bf.y + vs.y * as.y + bs.y;
    o.z = zi.z * af.z + bf.z + vs.z * as.z + bs.z;
    o.w = zi.w * af.w + bf.w + vs.w * as.w + bs.w;
    ((float4*)(out + (size_t)r * DOUT))[t] = o;
  }
}

// ---------------------------------------------------------------------------
extern "C" void kernel_launch(void* const* d_in, const int* in_sizes, int n_in,
                              void* d_out, int out_size, void* d_ws, size_t ws_size,
                              hipStream_t stream)
{
  const float* x     = (const float*)d_in[0];
  const float* W_fc  = (const float*)d_in[1];
  // d_in[2] = b_fc  : cancels in BN, unused
  const float* g_fc  = (const float*)d_in[3];
  const float* be_fc = (const float*)d_in[4];
  const float* W_sh  = (const float*)d_in[5];
  // d_in[6] = b_sh  : cancels in BN, unused
  const float* g_sh  = (const float*)d_in[7];
  const float* be_sh = (const float*)d_in[8];
  const int*   seg   = (const int*)d_in[9];
  float* out = (float*)d_out;

  char* w = (char*)d_ws;
  u16*   xbf  = (u16*)  (w);                       // 268435456 B
  u16*   xmbf = (u16*)  (w + 268435456);           //   4194304 B
  u16*   wfcb = (u16*)  (w + 272629760);           //   2097152 B
  u16*   wshb = (u16*)  (w + 274726912);           //   2097152 B
  float* zsub = (float*)(w + 276824064);           //   8388608 B  (z_s)
  float* pfS  = (float*)(w + 285212672);           //   4194304 B
  float* pfQ  = (float*)(w + 289406976);           //   4194304 B
  float* psS  = (float*)(w + 293601280);           //     65536 B
  float* psQ  = (float*)(w + 293666816);           //     65536 B
  float* scf  = (float*)(w + 293732352);           //      4096 B
  float* shf  = (float*)(w + 293736448);
  float* scs  = (float*)(w + 293740544);
  float* shs  = (float*)(w + 293744640);
  u16*   zbf  = (u16*)  (w + 293748736);           // 268435456 B (optional)
  const bool use_zbf = ws_size >= (size_t)293748736 + 268435456u;

  k_convw  <<<2048, 256, 0, stream>>>(W_fc, W_sh, wfcb, wshb);
  k_segsum <<<BB,   256, 0, stream>>>(x, seg, xbf, xmbf);

  if (use_zbf) gemm_kernel<1024, true ><<<8192, 256, 0, stream>>>(xbf, wfcb, (void*)zbf,  pfS, pfQ);
  else         gemm_kernel<1024, false><<<8192, 256, 0, stream>>>(xbf, wfcb, d_out,       pfS, pfQ);
  gemm_kernel<16, false><<<128, 256, 0, stream>>>(xmbf, wshb, (void*)zsub, psS, psQ);

  k_finalize<<<16, 256, 0, stream>>>(pfS, pfQ, 1024, 1.0f / (float)NN, g_fc, be_fc, scf, shf);
  k_finalize<<<16, 256, 0, stream>>>(psS, psQ, 16,   1.0f / (float)BB, g_sh, be_sh, scs, shs);

  if (use_zbf) k_epilogue<true ><<<8192, 256, 0, stream>>>((const void*)zbf, zsub, seg, scf, shf, scs, shs, out);
  else         k_epilogue<false><<<8192, 256, 0, stream>>>((const void*)d_out, zsub, seg, scf, shf, scs, shs, out);
}